// Round 6
// baseline (40.292 us; speedup 1.0000x reference)
//
#include <hip/hip_runtime.h>
#include <math.h>

typedef float f32x2 __attribute__((ext_vector_type(2)));

#define TWO_PI 6.283185307179586f
#define SMOOTH 0.1f
#define SPW 8                  // stations per WAVE
#define WAVES 4
#define BLOCK 256
#define SPB (SPW * WAVES)      // 32 stations per block
#define NPAIR 3                // column pairs per thread

__device__ __forceinline__ f32x2 sp2(float x) { f32x2 r; r.x = x; r.y = x; return r; }
__device__ __forceinline__ void store8(float* p, f32x2 v) { __builtin_memcpy(p, &v, 8); }
__device__ __forceinline__ float rlane(float v, int l) {
    return __uint_as_float((unsigned)__builtin_amdgcn_readlane((int)__float_as_uint(v), l));
}

// v5: zero-LDS. Every lane redundantly computes the coefficients of station
// wbase + (lane&7) (8-way redundant gather — same wave-wide cost, no
// divergence). The fully-unrolled j-loop broadcasts station j's 10 coefs
// from lane j via v_readlane -> SGPRs; inner FMAs use scalar coef operands.
// No LDS, no ds_read, no lgkmcnt stalls. SPW=8 doubles wave count for
// latency hiding / tail smoothing.
__global__ __launch_bounds__(BLOCK) void fused_v5(
    const float* __restrict__ time_vector,
    const float* __restrict__ constant_offset,
    const float* __restrict__ linear_trend,
    const float* __restrict__ amps,      // [N][4]
    const float* __restrict__ phs,       // [N][4]
    const float* __restrict__ wgt,       // [N][K]
    const float* __restrict__ periods,   // [4]
    const int*   __restrict__ nbidx,     // [N][K]
    float* __restrict__ out,             // [N][T]
    int N, int T, int K)
{
    const int tid   = threadIdx.x;
    const int wave  = tid >> 6;
    const int lane  = tid & 63;
    const int wbase = blockIdx.x * SPB + wave * SPW;

    if (wbase >= N) return;
    int send = N - wbase; if (send > SPW) send = SPW;

    // ---- Phase 1: all lanes compute coefs of station wbase+(lane&7) ----
    int sid = wbase + (lane & (SPW - 1));
    if (sid >= N) sid = N - 1;

    float4 a = reinterpret_cast<const float4*>(amps)[sid];
    float4 p = reinterpret_cast<const float4*>(phs)[sid];

    int   nb[5]; float w[5];
    __builtin_memcpy(nb, nbidx + (size_t)sid * K, 5 * sizeof(int));
    __builtin_memcpy(w,  wgt   + (size_t)sid * K, 5 * sizeof(float));

    float av0 = 0.f, av1 = 0.f, av2 = 0.f, av3 = 0.f;
    float pv0 = 0.f, pv1 = 0.f, pv2 = 0.f, pv3 = 0.f;
    #pragma unroll
    for (int k = 0; k < 5; ++k) {
        float4 na = reinterpret_cast<const float4*>(amps)[nb[k]];
        float4 np = reinterpret_cast<const float4*>(phs)[nb[k]];
        av0 += w[k] * na.x; av1 += w[k] * na.y; av2 += w[k] * na.z; av3 += w[k] * na.w;
        pv0 += w[k] * np.x; pv1 += w[k] * np.y; pv2 += w[k] * np.z; pv3 += w[k] * np.w;
    }
    float sa0 = (1.0f - SMOOTH) * a.x + SMOOTH * av0;
    float sa1 = (1.0f - SMOOTH) * a.y + SMOOTH * av1;
    float sa2 = (1.0f - SMOOTH) * a.z + SMOOTH * av2;
    float sa3 = (1.0f - SMOOTH) * a.w + SMOOTH * av3;
    float sp0 = (1.0f - SMOOTH) * p.x + SMOOTH * pv0;
    float sp1 = (1.0f - SMOOTH) * p.y + SMOOTH * pv1;
    float sp2v = (1.0f - SMOOTH) * p.z + SMOOTH * pv2;
    float sp3 = (1.0f - SMOOTH) * p.w + SMOOTH * pv3;

    // 10 coef VGPRs (lanes 0..7 are the broadcast sources)
    float cc = constant_offset[sid];
    float cm = linear_trend[sid];
    float cA0 = sa0 * __cosf(sp0),  cB0 = sa0 * __sinf(sp0);
    float cA1 = sa1 * __cosf(sp1),  cB1 = sa1 * __sinf(sp1);
    float cA2 = sa2 * __cosf(sp2v), cB2 = sa2 * __sinf(sp2v);
    float cA3 = sa3 * __cosf(sp3),  cB3 = sa3 * __sinf(sp3);

    // ---- Basis: 3 adjacent column pairs per thread, in registers ----
    const float w0 = TWO_PI / periods[0];
    const float w1 = TWO_PI / periods[1];
    const float w2 = TWO_PI / periods[2];
    const float w3 = TWO_PI / periods[3];

    f32x2 tv[NPAIR];
    f32x2 bs[NPAIR][4], bc[NPAIR][4];
    bool full[NPAIR], any[NPAIR];
    const int t0 = 2 * lane;

    #pragma unroll
    for (int q = 0; q < NPAIR; ++q) {
        const int t = t0 + 128 * q;
        const bool v0 = (t < T), v1 = (t + 1 < T);
        any[q] = v0; full[q] = v1;
        float ta = v0 ? time_vector[t]     : 0.f;
        float tb = v1 ? time_vector[t + 1] : 0.f;
        f32x2 tvp; tvp.x = ta; tvp.y = tb;
        tv[q] = tvp;
        #pragma unroll
        for (int f = 0; f < 4; ++f) {
            const float wf = (f == 0) ? w0 : (f == 1) ? w1 : (f == 2) ? w2 : w3;
            f32x2 s, c;
            s.x = __sinf(wf * ta); s.y = __sinf(wf * tb);
            c.x = __cosf(wf * ta); c.y = __cosf(wf * tb);
            bs[q][f] = s; bc[q][f] = c;
        }
    }

    // ---- j-loop: station j's coefs via readlane (SGPR broadcast) ----
    float* obase = out + (size_t)wbase * T;

    #pragma unroll
    for (int j = 0; j < SPW; ++j) {
        if (j >= send) break;                 // uniform branch
        float sc  = rlane(cc,  j), sm  = rlane(cm,  j);
        float sA0 = rlane(cA0, j), sB0 = rlane(cB0, j);
        float sA1 = rlane(cA1, j), sB1 = rlane(cB1, j);
        float sA2 = rlane(cA2, j), sB2 = rlane(cB2, j);
        float sA3 = rlane(cA3, j), sB3 = rlane(cB3, j);
        float* orow = obase + (size_t)j * T;

        #pragma unroll
        for (int q = 0; q < NPAIR; ++q) {
            f32x2 sig = sp2(sc) + sp2(sm) * tv[q];
            sig += sp2(sA0) * bs[q][0] + sp2(sB0) * bc[q][0];
            sig += sp2(sA1) * bs[q][1] + sp2(sB1) * bc[q][1];
            sig += sp2(sA2) * bs[q][2] + sp2(sB2) * bc[q][2];
            sig += sp2(sA3) * bs[q][3] + sp2(sB3) * bc[q][3];
            const int t = t0 + 128 * q;
            if (full[q])      store8(orow + t, sig);
            else if (any[q])  orow[t] = sig.x;
        }
    }
}

extern "C" void kernel_launch(void* const* d_in, const int* in_sizes, int n_in,
                              void* d_out, int out_size, void* d_ws, size_t ws_size,
                              hipStream_t stream)
{
    const float* time_vector     = (const float*)d_in[0];
    const float* constant_offset = (const float*)d_in[1];
    const float* linear_trend    = (const float*)d_in[2];
    const float* amps            = (const float*)d_in[3];
    const float* phs             = (const float*)d_in[4];
    const float* wgt             = (const float*)d_in[5];
    const float* periods         = (const float*)d_in[6];
    const int*   nbidx           = (const int*)d_in[7];

    int T = in_sizes[0];
    int N = in_sizes[1];
    int K = in_sizes[5] / N;
    float* out = (float*)d_out;

    int grid = (N + SPB - 1) / SPB;
    fused_v5<<<grid, BLOCK, 0, stream>>>(
        time_vector, constant_offset, linear_trend, amps, phs, wgt,
        periods, nbidx, out, N, T, K);
}